// Round 2
// 504.986 us; speedup vs baseline: 1.2371x; 1.2371x over previous
//
#include <hip/hip_runtime.h>

// J_row: 4096x4096 f32, J_col: 4096x4096 f32
// out[4][4096][4096] f32; group g = J_row[:, g*1024:(g+1)*1024] @ J_col[:, same]^T
// group 3: cols 3584:4096 scaled by 0.5 (folded into B during convert).

typedef unsigned short ushort_t;
typedef __bf16 bf16x8 __attribute__((ext_vector_type(8)));
typedef float floatx4 __attribute__((ext_vector_type(4)));
typedef unsigned short ushortx4 __attribute__((ext_vector_type(4)));

#define PDIM 4096
#define NG 4
#define BM 256
#define BN 256
#define BK 32
#define NBUF 4            // LDS ring depth (prefetch distance 3)
#define BUFE 16384        // ushorts per buffer: A 256*32 + B 256*32 = 32 KB
#define NT 128            // K tiles = 4096/32
#define GT 32             // K tiles per group = 1024/32

__device__ __forceinline__ unsigned short f2bf_rne(float f) {
  union { float f; unsigned u; } v; v.f = f;
  unsigned u = v.u;
  unsigned r = u + 0x7FFFu + ((u >> 16) & 1u);
  return (unsigned short)(r >> 16);
}

// Fully dense convert: 4 elems/thread, contiguous float4 load + 8B store.
// blockIdx.y==1 (J_col) scales cols >= 3584 by 0.5.
__global__ void convert_bf16(const float* __restrict__ srcA,
                             const float* __restrict__ srcB,
                             ushort_t* __restrict__ dstA,
                             ushort_t* __restrict__ dstB) {
  const float* src; ushort_t* dst; int scale_start;
  if (blockIdx.y == 0) { src = srcA; dst = dstA; scale_start = PDIM; }
  else                 { src = srcB; dst = dstB; scale_start = 3584; }
  long long base = ((long long)blockIdx.x * blockDim.x + threadIdx.x) * 4;
  int col = (int)(base & (PDIM - 1));       // 4-aligned; 3584 is 4-aligned
  float s = (col >= scale_start) ? 0.5f : 1.0f;
  float4 x = *(const float4*)(src + base);
  ushortx4 o;
  o[0] = f2bf_rne(x.x * s); o[1] = f2bf_rne(x.y * s);
  o[2] = f2bf_rne(x.z * s); o[3] = f2bf_rne(x.w * s);
  *(ushortx4*)(dst + base) = o;
}

__device__ __forceinline__ void async_copy16(const ushort_t* g, ushort_t* l) {
  __builtin_amdgcn_global_load_lds(
      (const __attribute__((address_space(1))) unsigned int*)(g),
      (__attribute__((address_space(3))) unsigned int*)(l),
      16, 0, 0);
}

// 256x256 tile, BK=32, 8 waves (2M x 4N), per-wave C = 128x64 (8x4 frags).
// 4-deep LDS ring buffer; stage(t+3) issued at iter t; counted s_waitcnt
// vmcnt(8) + raw s_barrier once per K-tile (no vmcnt(0) drain in steady
// state).  K runs 0..4096 continuously; accumulator flushed every 32 tiles
// (one group).  Ab/Bb contiguous in workspace -> single base + u32 offsets.
__global__ __launch_bounds__(512, 2) void gemm_grouped(
    const ushort_t* __restrict__ Ab, float* __restrict__ out) {
  __shared__ ushort_t lds[NBUF * BUFE];   // 128 KB

  const int tid = threadIdx.x;
  const int wave = tid >> 6;
  const int lane = tid & 63;
  const int m16 = lane & 15;
  const int quad = lane >> 4;
  const int wm = wave >> 2;     // 0..1
  const int wn = wave & 3;      // 0..3

  // XCD-aware swizzle: 256 blocks -> each XCD owns a 4x8 tile chunk.
  const int bid = blockIdx.x;
  const int xcd = bid & 7;
  const int loc = bid >> 3;                        // 0..31
  const int tm = (xcd >> 1) * 4 + (loc >> 3);      // 0..15
  const int tn = (xcd & 1) * 8 + (loc & 7);        // 0..15
  const int row0 = tm * BM;
  const int col0 = tn * BN;

  // Staging: 32 chunks of 1KB per K-tile (A: q(0..3) x c(0..3) 64-row
  // groups; B same), 4 chunks per wave, 4 x global_load_lds(16B)/thread.
  // XOR row swizzle by (q<<1) on the global-read side (LDS stays linear;
  // fragment ds_read_b128 then spreads banks -> measured 0 conflicts).
  unsigned goff[4];
  int lbase[4];
#pragma unroll
  for (int s = 0; s < 4; ++s) {
    int ch = wave * 4 + s;       // 0..31
    int isB = ch >> 4;
    int ch2 = ch & 15;
    int q = ch2 >> 2;            // k-chunk (8 cols)
    int c = ch2 & 3;             // 64-row group
    int grow = (isB ? col0 : row0) + c * 64 + (lane ^ (q << 1));
    goff[s] = (unsigned)isB * (unsigned)(PDIM * PDIM) +
              (unsigned)grow * (unsigned)PDIM + (unsigned)(q * 8);
    lbase[s] = isB * 8192 + q * 2048 + c * 512;
  }

  // Fragment LDS element offsets within one buffer.
  // A frag i: rows wm*128 + i*16 + m16, k-chunk quad.
  int a_off[8], b_off[4];
#pragma unroll
  for (int i = 0; i < 8; ++i)
    a_off[i] = quad * 2048 + (wm * 128 + i * 16 + (m16 ^ (quad << 1))) * 8;
#pragma unroll
  for (int j = 0; j < 4; ++j)
    b_off[j] = 8192 + quad * 2048 + (wn * 64 + j * 16 + (m16 ^ (quad << 1))) * 8;

  const int orow0 = row0 + wm * 128 + quad * 4;
  const int ocol0 = col0 + wn * 64 + m16;

  floatx4 acc[8][4];
#pragma unroll
  for (int i = 0; i < 8; ++i)
#pragma unroll
    for (int j = 0; j < 4; ++j)
      acc[i][j] = (floatx4){0.f, 0.f, 0.f, 0.f};

  auto stage = [&](int t) {
    unsigned kcol = (unsigned)(t * BK);
    int lb = (t & (NBUF - 1)) * BUFE;
#pragma unroll
    for (int s = 0; s < 4; ++s)
      async_copy16(Ab + goff[s] + kcol, &lds[lb + lbase[s]]);
  };

  // Prologue: fill pipeline 3 deep; own vmcnt(8) leaves only t=1,2 chunks
  // in flight -> own tile-0 chunks landed; barrier makes it all-waves.
  stage(0); stage(1); stage(2);
  asm volatile("s_waitcnt vmcnt(8)" ::: "memory");
  __builtin_amdgcn_s_barrier();

  for (int t = 0; t < NT; ++t) {
    if (t + 3 < NT) stage(t + 3);

    const ushort_t* lb = &lds[(t & (NBUF - 1)) * BUFE];
    bf16x8 af[8], bf[4];
#pragma unroll
    for (int i = 0; i < 8; ++i) af[i] = *(const bf16x8*)(lb + a_off[i]);
#pragma unroll
    for (int j = 0; j < 4; ++j) bf[j] = *(const bf16x8*)(lb + b_off[j]);

    __builtin_amdgcn_s_setprio(1);
#pragma unroll
    for (int i = 0; i < 8; ++i)
#pragma unroll
      for (int j = 0; j < 4; ++j)
        acc[i][j] = __builtin_amdgcn_mfma_f32_16x16x32_bf16(
            af[i], bf[j], acc[i][j], 0, 0, 0);
    __builtin_amdgcn_s_setprio(0);

    // Counted wait: outstanding = own stages for t+1,t+2,t+3 (12 loads);
    // vmcnt(8) retires tile t+1.  Tail peels to 4 then 0 as stages stop.
    if (t < NT - 3)       asm volatile("s_waitcnt vmcnt(8)" ::: "memory");
    else if (t == NT - 3) asm volatile("s_waitcnt vmcnt(4)" ::: "memory");
    else                  asm volatile("s_waitcnt vmcnt(0)" ::: "memory");
    __builtin_amdgcn_s_barrier();

    if (((t + 1) & (GT - 1)) == 0) {
      // Flush group g; C/D layout: col = lane&15, row = quad*4 + v.
      const int g = t >> 5;
      float* outp = out + (size_t)g * PDIM * PDIM;
#pragma unroll
      for (int i = 0; i < 8; ++i)
#pragma unroll
        for (int j = 0; j < 4; ++j) {
#pragma unroll
          for (int v = 0; v < 4; ++v)
            outp[(size_t)(orow0 + i * 16 + v) * PDIM + (ocol0 + j * 16)] =
                acc[i][j][v];
          acc[i][j] = (floatx4){0.f, 0.f, 0.f, 0.f};
        }
    }
  }
}

extern "C" void kernel_launch(void* const* d_in, const int* in_sizes, int n_in,
                              void* d_out, int out_size, void* d_ws, size_t ws_size,
                              hipStream_t stream) {
  const float* J_row = (const float*)d_in[0];
  const float* J_col = (const float*)d_in[1];
  float* out = (float*)d_out;

  ushort_t* Ab = (ushort_t*)d_ws;                  // 32 MB
  ushort_t* Bb = Ab + (size_t)PDIM * PDIM;         // 32 MB, contiguous after A

  dim3 cgrid(PDIM * PDIM / 4 / 256, 2);            // (16384, 2)
  convert_bf16<<<cgrid, 256, 0, stream>>>(J_row, J_col, Ab, Bb);

  gemm_grouped<<<dim3(256), 512, 0, stream>>>(Ab, out);
}

// Round 3
// 467.233 us; speedup vs baseline: 1.3371x; 1.0808x over previous
//
#include <hip/hip_runtime.h>

// J_row: 4096x4096 f32, J_col: 4096x4096 f32
// out[4][4096][4096] f32; group g = J_row[:, g*1024:(g+1)*1024] @ J_col[:, same]^T
// group 3: cols 3584:4096 scaled by 0.5 (folded into B during convert).
//
// Workspace holds a PACKED bf16 copy of both matrices:
//   P[mat][kt][m][slot], slot = kchunk ^ ((m>>1)&3)   (bank swizzle baked in)
// so each K-tile's 256x32 panel is a contiguous 16 KB span -> staging
// global_load_lds reads are fully contiguous (8x128B txns per 1KB instr
// instead of 64 scattered lines), which was the round-2 bottleneck.

typedef unsigned short ushort_t;
typedef __bf16 bf16x8 __attribute__((ext_vector_type(8)));
typedef float floatx4 __attribute__((ext_vector_type(4)));
typedef unsigned short ushortx8 __attribute__((ext_vector_type(8)));

#define PDIM 4096
#define BM 256
#define BN 256
#define BK 32
#define NBUF 4             // LDS ring depth (prefetch distance 3)
#define BUFE 16384         // ushorts per ring slot: A 8192 + B 8192 = 32 KB
#define NT 128             // K tiles
#define GT 32              // K tiles per group
#define KTSZ (PDIM * BK)   // ushorts per packed k-tile plane (131072)

__device__ __forceinline__ unsigned short f2bf_rne(float f) {
  union { float f; unsigned u; } v; v.f = f;
  unsigned u = v.u;
  unsigned r = u + 0x7FFFu + ((u >> 16) & 1u);
  return (unsigned short)(r >> 16);
}

// Convert + pack. Block = 256 threads over a [64 rows x 32 cols] tile of one
// (mat, kt, mb). Thread (r = tid>>2, s = tid&3): reads 8 f32 (32B, row-major,
// lines fully used), writes 16B at packed slot s^((row>>1)&3) -> each wave's
// 64 stores cover a contiguous 1 KB of the packed plane.
__global__ void convert_pack(const float* __restrict__ srcA,
                             const float* __restrict__ srcB,
                             ushort_t* __restrict__ dst) {
  const int mat = blockIdx.y;
  const float* src = mat ? srcB : srcA;
  const int kt = blockIdx.x & 127;
  const int mb = blockIdx.x >> 7;
  const int r = threadIdx.x >> 2;
  const int s = threadIdx.x & 3;
  const int row = mb * 64 + r;
  const float sc = (mat && kt >= 112) ? 0.5f : 1.0f;   // cols>=3584

  const float* p = src + (size_t)row * PDIM + kt * 32 + s * 8;
  float4 x = *(const float4*)p;
  float4 y = *(const float4*)(p + 4);
  ushortx8 o;
  o[0] = f2bf_rne(x.x * sc); o[1] = f2bf_rne(x.y * sc);
  o[2] = f2bf_rne(x.z * sc); o[3] = f2bf_rne(x.w * sc);
  o[4] = f2bf_rne(y.x * sc); o[5] = f2bf_rne(y.y * sc);
  o[6] = f2bf_rne(y.z * sc); o[7] = f2bf_rne(y.w * sc);

  const int slot = s ^ ((row >> 1) & 3);
  ushort_t* q = dst + (size_t)mat * PDIM * PDIM + (size_t)kt * KTSZ +
                row * 32 + slot * 8;
  *(ushortx8*)q = o;
}

__device__ __forceinline__ void async_copy16(const ushort_t* g, ushort_t* l) {
  __builtin_amdgcn_global_load_lds(
      (const __attribute__((address_space(1))) unsigned int*)(g),
      (__attribute__((address_space(3))) unsigned int*)(l),
      16, 0, 0);
}

// 256x256 tile, BK=32, 8 waves (2M x 4N), per-wave C = 128x64 (8x4 frags).
// 4-deep LDS ring; stage(t+3) at iter t; counted vmcnt(8) + one s_barrier
// per K-tile (never drains to 0 in steady state). Accumulator flushed to
// out[g] every 32 tiles.
__global__ __launch_bounds__(512, 2) void gemm_grouped(
    const ushort_t* __restrict__ P, float* __restrict__ out) {
  __shared__ ushort_t lds[NBUF * BUFE];   // 128 KB

  const int tid = threadIdx.x;
  const int wave = tid >> 6;
  const int lane = tid & 63;
  const int m16 = lane & 15;
  const int quad = lane >> 4;
  const int wm = wave >> 2;     // 0..1
  const int wn = wave & 3;      // 0..3

  // XCD-aware swizzle: 256 blocks -> each XCD owns a 4x8 tile chunk.
  const int bid = blockIdx.x;
  const int xcd = bid & 7;
  const int loc = bid >> 3;                        // 0..31
  const int tm = (xcd >> 1) * 4 + (loc >> 3);      // 0..15
  const int tn = (xcd & 1) * 8 + (loc & 7);        // 0..15
  const int row0 = tm * BM;
  const int col0 = tn * BN;

  // Staging: 32 contiguous 1KB chunks per K-tile (A: 16, B: 16), 4 per wave.
  // Chunk ch covers packed rows (row0|col0) + (ch&15)*16 .. +15 (contiguous).
  // Waves 0-3 stage A, waves 4-7 stage B. LDS dest is wave-uniform + lane*16.
  unsigned goff[4];
  int lbase[4];
#pragma unroll
  for (int s = 0; s < 4; ++s) {
    int ch = wave * 4 + s;       // 0..31
    int isB = ch >> 4;
    int chloc = ch & 15;
    goff[s] = (unsigned)isB * (unsigned)(PDIM * PDIM) +
              (unsigned)((isB ? col0 : row0) * 32 + chloc * 512 + lane * 8);
    lbase[s] = isB * 8192 + chloc * 512;
  }

  // Fragment LDS offsets (ushorts) within one ring slot.
  // Packed layout: row-major [m][32] with k-chunk at slot quad^((m>>1)&3).
  // Bank check: dword idx = 16*row + 4*slot + j -> 16 lanes/quad cover 8
  // bank-quads 2-way (free); full wave = 8 lanes/bank-quad = min phases.
  int a_off[8], b_off[4];
  const int ksl = (quad ^ ((m16 >> 1) & 3)) * 8;
#pragma unroll
  for (int i = 0; i < 8; ++i)
    a_off[i] = (wm * 128 + i * 16 + m16) * 32 + ksl;
#pragma unroll
  for (int j = 0; j < 4; ++j)
    b_off[j] = 8192 + (wn * 64 + j * 16 + m16) * 32 + ksl;

  const int orow0 = row0 + wm * 128 + quad * 4;
  const int ocol0 = col0 + wn * 64 + m16;

  floatx4 acc[8][4];
#pragma unroll
  for (int i = 0; i < 8; ++i)
#pragma unroll
    for (int j = 0; j < 4; ++j)
      acc[i][j] = (floatx4){0.f, 0.f, 0.f, 0.f};

  auto stage = [&](int t) {
    const ushort_t* gbase = P + (size_t)t * KTSZ;
    int lb = (t & (NBUF - 1)) * BUFE;
#pragma unroll
    for (int s = 0; s < 4; ++s)
      async_copy16(gbase + goff[s], &lds[lb + lbase[s]]);
  };

  // Prologue: fill 3 deep; vmcnt(8) retires own tile-0 loads; barrier
  // extends that to all waves.
  stage(0); stage(1); stage(2);
  asm volatile("s_waitcnt vmcnt(8)" ::: "memory");
  __builtin_amdgcn_s_barrier();

  for (int t = 0; t < NT; ++t) {
    if (t + 3 < NT) stage(t + 3);

    const ushort_t* lb = &lds[(t & (NBUF - 1)) * BUFE];
    bf16x8 af[8], bf[4];
#pragma unroll
    for (int i = 0; i < 8; ++i) af[i] = *(const bf16x8*)(lb + a_off[i]);
#pragma unroll
    for (int j = 0; j < 4; ++j) bf[j] = *(const bf16x8*)(lb + b_off[j]);

    __builtin_amdgcn_s_setprio(1);
#pragma unroll
    for (int i = 0; i < 8; ++i)
#pragma unroll
      for (int j = 0; j < 4; ++j)
        acc[i][j] = __builtin_amdgcn_mfma_f32_16x16x32_bf16(
            af[i], bf[j], acc[i][j], 0, 0, 0);
    __builtin_amdgcn_s_setprio(0);

    // Counted wait: 12 own loads outstanding (t+1..t+3); vmcnt(8) retires
    // tile t+1. Tail peels 8 -> 4 -> 0.
    if (t < NT - 3)       asm volatile("s_waitcnt vmcnt(8)" ::: "memory");
    else if (t == NT - 3) asm volatile("s_waitcnt vmcnt(4)" ::: "memory");
    else                  asm volatile("s_waitcnt vmcnt(0)" ::: "memory");
    __builtin_amdgcn_s_barrier();

    if (((t + 1) & (GT - 1)) == 0) {
      // Flush group g; C/D layout: col = lane&15, row = quad*4 + v.
      const int g = t >> 5;
      float* outp = out + (size_t)g * PDIM * PDIM;
#pragma unroll
      for (int i = 0; i < 8; ++i)
#pragma unroll
        for (int j = 0; j < 4; ++j) {
#pragma unroll
          for (int v = 0; v < 4; ++v)
            outp[(size_t)(orow0 + i * 16 + v) * PDIM + (ocol0 + j * 16)] =
                acc[i][j][v];
          acc[i][j] = (floatx4){0.f, 0.f, 0.f, 0.f};
        }
    }
  }
}

extern "C" void kernel_launch(void* const* d_in, const int* in_sizes, int n_in,
                              void* d_out, int out_size, void* d_ws, size_t ws_size,
                              hipStream_t stream) {
  const float* J_row = (const float*)d_in[0];
  const float* J_col = (const float*)d_in[1];
  float* out = (float*)d_out;

  ushort_t* P = (ushort_t*)d_ws;   // 64 MB packed bf16 (A then B)

  dim3 cgrid(128 * 64, 2);         // (kt, mb) x matrix
  convert_pack<<<cgrid, 256, 0, stream>>>(J_row, J_col, P);

  gemm_grouped<<<dim3(256), 512, 0, stream>>>(P, out);
}